// Round 7
// baseline (13.449 us; speedup 1.0000x reference)
//
#include <hip/hip_runtime.h>

// Problem constants: B=32, M=12, T=512, G=256
#define B_ 32
#define M_ 12
#define T_ 512
#define G_ 256

#define GS 16              // g-values per block (2 per thread)
#define NBLK 512           // 32 b * 16 g-chunks
#define TPAIR 256          // T/2 t-pairs
#define ROWW 18            // u32 row stride: stride/2 odd -> b64 reads hit 16
                           // distinct 8B bank windows (4 lanes each = floor)

// dens[b,g,m] = sum_t mask[b,m,t]*exp(-0.5*(grid[g]-x[b,t])^2/s0^2)
// conv[b,g,m] = sum_t    y[b,m,t]*exp(-0.5*(grid[g]-x[b,t])^2/s1^2)
// out[b][g][2m] = dens ; out[b][g][2m+1] = conv/(dens+1e-8)

using h2 = decltype(__builtin_amdgcn_cvt_pkrtz(0.f, 0.f));

__device__ __forceinline__ float fdot2f(h2 a, h2 b, float c) {
#if __has_builtin(__builtin_amdgcn_fdot2)
    return __builtin_amdgcn_fdot2(a, b, c, false);
#else
    return c + (float)a[0] * (float)b[0] + (float)a[1] * (float)b[1];
#endif
}

// Payload-halving butterfly step for d<=16 (ds_swizzle xor within 32-groups).
// N = unit count before this step; keeps N/2.
template <int D, int N, int IMM>
__device__ __forceinline__ void red_step(float2* U, int ls) {
    const bool bit = (ls & D) != 0;
#pragma unroll
    for (int i = 0; i < N / 2; ++i) {
        const float2 lo = U[i], hi = U[i + N / 2];
        const float2 snd = bit ? lo : hi;
        float2 rcv;
        rcv.x = __uint_as_float(
            (unsigned)__builtin_amdgcn_ds_swizzle((int)__float_as_uint(snd.x), IMM));
        rcv.y = __uint_as_float(
            (unsigned)__builtin_amdgcn_ds_swizzle((int)__float_as_uint(snd.y), IMM));
        const float2 kp = bit ? hi : lo;
        U[i] = make_float2(kp.x + rcv.x, kp.y + rcv.y);
    }
}

// d=32 halving step via permlane32_swap (VALU pipe).
// ret[0][ls] = snd[ls & 31], ret[1][ls] = snd[ls | 32]; partner snd[ls^32] is
// ret[1] for lanes<32 (bit=0), ret[0] for lanes>=32 (verified R6).
template <int N>
__device__ __forceinline__ void red_step32(float2* U, int ls) {
    const bool bit = (ls & 32) != 0;
#pragma unroll
    for (int i = 0; i < N / 2; ++i) {
        const float2 lo = U[i], hi = U[i + N / 2];
        const float2 snd = bit ? lo : hi;
        float2 rcv;
#if __has_builtin(__builtin_amdgcn_permlane32_swap)
        {
            auto rx = __builtin_amdgcn_permlane32_swap(
                __float_as_uint(snd.x), __float_as_uint(snd.x), false, false);
            auto ry = __builtin_amdgcn_permlane32_swap(
                __float_as_uint(snd.y), __float_as_uint(snd.y), false, false);
            rcv.x = __uint_as_float(bit ? rx[0] : rx[1]);
            rcv.y = __uint_as_float(bit ? ry[0] : ry[1]);
        }
#else
        rcv.x = __shfl_xor(snd.x, 32, 64);
        rcv.y = __shfl_xor(snd.y, 32, 64);
#endif
        const float2 kp = bit ? hi : lo;
        U[i] = make_float2(kp.x + rcv.x, kp.y + rcv.y);
    }
}

__global__ __launch_bounds__(512, 4) void k_fused(
    const float* __restrict__ y, const float* __restrict__ x,
    const int* __restrict__ mask, const float* __restrict__ grid,
    const float* __restrict__ sigma, float* __restrict__ out)
{
    __shared__ unsigned int sy[TPAIR * ROWW];   // f16(y) pairs, [tp][m]
    __shared__ unsigned int sm[TPAIR * ROWW];   // f16(mask) pairs

    // XCD-pinned mapping: xcd = bid&7 owns 64 blocks = 4 consecutive b's.
    const int bid = blockIdx.x;
    const int w   = ((bid & 7) << 6) | (bid >> 3);   // bijective, w < 512
    const int b   = w >> 4;            // 0..31
    const int gb  = (w & 15) * GS;     // g-chunk base

    const int tid = threadIdx.x;
    const int gq  = tid >> 6;          // wave id 0..7
    const int ls  = tid & 63;          // lane: t-slice

    // x pairs -> registers (coalesced)
    float2 xp[4];
#pragma unroll
    for (int k = 0; k < 4; ++k)
        xp[k] = *(const float2*)&x[b * T_ + 2 * (ls + 64 * k)];

    // stage y+mask as f16 pairs; coalesced float2/int2 global reads
#pragma unroll
    for (int it = 0; it < 6; ++it) {
        const int i  = tid + 512 * it;
        const int m  = i >> 8;         // 0..11
        const int tp = i & 255;
        const float2 yv = *(const float2*)&y[(b * M_ + m) * T_ + 2 * tp];
        auto yh = __builtin_amdgcn_cvt_pkrtz(yv.x, yv.y);
        sy[tp * ROWW + m] = __builtin_bit_cast(unsigned int, yh);
        const int2 mv = *(const int2*)&mask[(b * M_ + m) * T_ + 2 * tp];
        sm[tp * ROWW + m] = (mv.x ? 0x3C00u : 0u) | (mv.y ? 0x3C000000u : 0u);
    }
    __syncthreads();

    float gv[2];
#pragma unroll
    for (int h = 0; h < 2; ++h) gv[h] = grid[gb + gq + 8 * h];
    const float s0 = sigma[0], s1 = sigma[1];
    const float LOG2E = 1.4426950408889634f;
    const float c0 = (-0.5f / (s0 * s0)) * LOG2E;
    const float c1 = (-0.5f / (s1 * s1)) * LOG2E;

    float accD[2][12], accC[2][12];
#pragma unroll
    for (int h = 0; h < 2; ++h)
#pragma unroll
        for (int m = 0; m < 12; ++m) { accD[h][m] = 0.f; accC[h][m] = 0.f; }

#pragma unroll
    for (int k = 0; k < 4; ++k) {
        const int tp = ls + 64 * k;
        const float2 xv = xp[k];
        h2 w0[2], w1[2];
#pragma unroll
        for (int h = 0; h < 2; ++h) {
            const float d0 = gv[h] - xv.x, d1 = gv[h] - xv.y;
            const float p0 = d0 * d0, p1 = d1 * d1;
            w0[h] = __builtin_amdgcn_cvt_pkrtz(__builtin_amdgcn_exp2f(p0 * c0),
                                               __builtin_amdgcn_exp2f(p1 * c0));
            w1[h] = __builtin_amdgcn_cvt_pkrtz(__builtin_amdgcn_exp2f(p0 * c1),
                                               __builtin_amdgcn_exp2f(p1 * c1));
        }
        const unsigned int* ry = &sy[tp * ROWW];
        const unsigned int* rm = &sm[tp * ROWW];
#pragma unroll
        for (int j = 0; j < 6; ++j) {
            const uint2 yv2 = *(const uint2*)&ry[2 * j];   // b64, 8B-aligned
            const uint2 mv2 = *(const uint2*)&rm[2 * j];
            const h2 yp0 = __builtin_bit_cast(h2, yv2.x);
            const h2 yp1 = __builtin_bit_cast(h2, yv2.y);
            const h2 mp0 = __builtin_bit_cast(h2, mv2.x);
            const h2 mp1 = __builtin_bit_cast(h2, mv2.y);
#pragma unroll
            for (int h = 0; h < 2; ++h) {
                accD[h][2 * j]     = fdot2f(mp0, w0[h], accD[h][2 * j]);
                accC[h][2 * j]     = fdot2f(yp0, w1[h], accC[h][2 * j]);
                accD[h][2 * j + 1] = fdot2f(mp1, w0[h], accD[h][2 * j + 1]);
                accC[h][2 * j + 1] = fdot2f(yp1, w1[h], accC[h][2 * j + 1]);
            }
        }
    }

    // ---- butterfly reduction across the 64 t-lanes ----
    // 32 units: u = mm*2 + h (mm<16, real mm<12; h<2). Steps d=32..2 halve the
    // payload (consuming u-bits MSB->LSB), final d=1 is a plain exchange+add.
    // After all steps lane ls holds unit u = ls>>1 in U[0].
    float2 U[32];
#pragma unroll
    for (int mm = 0; mm < 16; ++mm)
#pragma unroll
        for (int h = 0; h < 2; ++h)
            U[mm * 2 + h] = (mm < 12) ? make_float2(accD[h][mm], accC[h][mm])
                                      : make_float2(0.f, 0.f);

    red_step32<32>(U, ls);              // 32 -> 16
    red_step<16, 16, 0x401F>(U, ls);    // 16 -> 8
    red_step<8,   8, 0x201F>(U, ls);    //  8 -> 4
    red_step<4,   4, 0x101F>(U, ls);    //  4 -> 2
    red_step<2,   2, 0x081F>(U, ls);    //  2 -> 1
    {   // final d=1: non-halving exchange+add (both lanes keep full sum)
        float2 rcv;
        rcv.x = __uint_as_float(
            (unsigned)__builtin_amdgcn_ds_swizzle((int)__float_as_uint(U[0].x), 0x041F));
        rcv.y = __uint_as_float(
            (unsigned)__builtin_amdgcn_ds_swizzle((int)__float_as_uint(U[0].y), 0x041F));
        U[0].x += rcv.x;
        U[0].y += rcv.y;
    }

    const int mm = ls >> 2;             // unit u = ls>>1: mm = u>>1
    const int h  = (ls >> 1) & 1;       // h = u&1
    if ((ls & 1) == 0 && mm < 12) {
        const int g = gb + gq + 8 * h;
        const float dens = U[0].x;
        float2 o;
        o.x = dens;
        o.y = U[0].y / (dens + 1e-8f);
        *(float2*)&out[(size_t)(b * G_ + g) * (2 * M_) + 2 * mm] = o;
    }
}

extern "C" void kernel_launch(void* const* d_in, const int* in_sizes, int n_in,
                              void* d_out, int out_size, void* d_ws, size_t ws_size,
                              hipStream_t stream) {
    const float* y     = (const float*)d_in[0];
    const float* x     = (const float*)d_in[1];
    const int*   mask  = (const int*)d_in[2];
    const float* grid  = (const float*)d_in[3];
    const float* sigma = (const float*)d_in[4];
    float* out = (float*)d_out;
    (void)d_ws; (void)ws_size;

    k_fused<<<NBLK, 512, 0, stream>>>(y, x, mask, grid, sigma, out);
}

// Round 8
// 12.601 us; speedup vs baseline: 1.0673x; 1.0673x over previous
//
#include <hip/hip_runtime.h>

// Problem constants: B=32, M=12, T=512, G=256
#define B_ 32
#define M_ 12
#define T_ 512
#define G_ 256

#define GS 16              // g-values per block (2 per thread: h=0,1)
#define NBLK 512           // 32 b * 16 g-chunks
#define TPAIR 256          // T/2 t-pairs
#define ROWW 18            // u32 row stride: 18*tp mod 32 covers all 16 even
                           // bank starts -> b64 reads AND paired b64 writes
                           // run at the 4-cycle wave-b64 floor

// dens[b,g,m] = sum_t mask[b,m,t]*exp(-0.5*(grid[g]-x[b,t])^2/s0^2)
// conv[b,g,m] = sum_t    y[b,m,t]*exp(-0.5*(grid[g]-x[b,t])^2/s1^2)
// out[b][g][2m] = dens ; out[b][g][2m+1] = conv/(dens+1e-8)

using h2 = decltype(__builtin_amdgcn_cvt_pkrtz(0.f, 0.f));

__device__ __forceinline__ float fdot2f(h2 a, h2 b, float c) {
#if __has_builtin(__builtin_amdgcn_fdot2)
    return __builtin_amdgcn_fdot2(a, b, c, false);
#else
    return c + (float)a[0] * (float)b[0] + (float)a[1] * (float)b[1];
#endif
}

__device__ __forceinline__ float2 swz_f2(float2 v, int imm_encoded_as_template);

template <int IMM>
__device__ __forceinline__ float2 swz2(float2 v) {
    float2 r;
    r.x = __uint_as_float(
        (unsigned)__builtin_amdgcn_ds_swizzle((int)__float_as_uint(v.x), IMM));
    r.y = __uint_as_float(
        (unsigned)__builtin_amdgcn_ds_swizzle((int)__float_as_uint(v.y), IMM));
    return r;
}

__global__ __launch_bounds__(512, 4) void k_fused(
    const float* __restrict__ y, const float* __restrict__ x,
    const int* __restrict__ mask, const float* __restrict__ grid,
    const float* __restrict__ sigma, float* __restrict__ out)
{
    __shared__ unsigned int sy[TPAIR * ROWW];   // 18,432 B: f16(y) pairs [tp][m]
    __shared__ unsigned int sm[TPAIR * ROWW];   // 18,432 B: f16(mask) pairs
    __shared__ float dmp[8 * 64 * 3 * 2];       // 12,288 B: (wave,lane,slot) float2

    // XCD-pinned mapping: xcd = bid&7 owns 64 blocks = 4 consecutive b's.
    const int bid = blockIdx.x;
    const int w   = ((bid & 7) << 6) | (bid >> 3);   // bijective, w < 512
    const int b   = w >> 4;            // 0..31
    const int gb  = (w & 15) * GS;     // g-chunk base

    const int tid = threadIdx.x;
    const int gq  = tid >> 6;          // wave id 0..7
    const int ls  = tid & 63;          // lane: t-slice

    // x pairs -> registers (coalesced)
    float2 xp[4];
#pragma unroll
    for (int k = 0; k < 4; ++k)
        xp[k] = *(const float2*)&x[b * T_ + 2 * (ls + 64 * k)];

    // stage y+mask as f16 t-pairs; per iter one (tp, m-pair): 4x 8B global
    // loads (coalesced) + 2x b64 LDS writes at the bank floor.
#pragma unroll
    for (int it = 0; it < 3; ++it) {
        const int i  = tid + 512 * it;     // 0..1535
        const int mp = i >> 8;             // 0..5  (m-pair)
        const int tp = i & 255;
        const int m0 = 2 * mp;
        const float2 y0 = *(const float2*)&y[(b * M_ + m0) * T_ + 2 * tp];
        const float2 y1 = *(const float2*)&y[(b * M_ + m0 + 1) * T_ + 2 * tp];
        uint2 yw;
        yw.x = __builtin_bit_cast(unsigned int, __builtin_amdgcn_cvt_pkrtz(y0.x, y0.y));
        yw.y = __builtin_bit_cast(unsigned int, __builtin_amdgcn_cvt_pkrtz(y1.x, y1.y));
        *(uint2*)&sy[tp * ROWW + 2 * mp] = yw;
        const int2 ma = *(const int2*)&mask[(b * M_ + m0) * T_ + 2 * tp];
        const int2 mb = *(const int2*)&mask[(b * M_ + m0 + 1) * T_ + 2 * tp];
        uint2 mw;
        mw.x = (ma.x ? 0x3C00u : 0u) | (ma.y ? 0x3C000000u : 0u);
        mw.y = (mb.x ? 0x3C00u : 0u) | (mb.y ? 0x3C000000u : 0u);
        *(uint2*)&sm[tp * ROWW + 2 * mp] = mw;
    }
    __syncthreads();

    float gv[2];
#pragma unroll
    for (int h = 0; h < 2; ++h) gv[h] = grid[gb + gq + 8 * h];
    const float s0 = sigma[0], s1 = sigma[1];
    const float LOG2E = 1.4426950408889634f;
    const float c0 = (-0.5f / (s0 * s0)) * LOG2E;
    const float c1 = (-0.5f / (s1 * s1)) * LOG2E;
    const bool same = (c0 == c1);   // wave-uniform; true for the given inputs

    float accD[2][12], accC[2][12];
#pragma unroll
    for (int h = 0; h < 2; ++h)
#pragma unroll
        for (int m = 0; m < 12; ++m) { accD[h][m] = 0.f; accC[h][m] = 0.f; }

#pragma unroll
    for (int k = 0; k < 4; ++k) {
        const int tp = ls + 64 * k;
        const float2 xv = xp[k];
        h2 w0[2], w1[2];
#pragma unroll
        for (int h = 0; h < 2; ++h) {
            const float d0 = gv[h] - xv.x, d1 = gv[h] - xv.y;
            const float p0 = d0 * d0, p1 = d1 * d1;
            w0[h] = __builtin_amdgcn_cvt_pkrtz(__builtin_amdgcn_exp2f(p0 * c0),
                                               __builtin_amdgcn_exp2f(p1 * c0));
            w1[h] = same ? w0[h]
                         : __builtin_amdgcn_cvt_pkrtz(__builtin_amdgcn_exp2f(p0 * c1),
                                                      __builtin_amdgcn_exp2f(p1 * c1));
        }
        const unsigned int* ry = &sy[tp * ROWW];
        const unsigned int* rm = &sm[tp * ROWW];
#pragma unroll
        for (int j = 0; j < 6; ++j) {
            const uint2 yv2 = *(const uint2*)&ry[2 * j];   // b64, 8B-aligned
            const uint2 mv2 = *(const uint2*)&rm[2 * j];
            const h2 yp0 = __builtin_bit_cast(h2, yv2.x);
            const h2 yp1 = __builtin_bit_cast(h2, yv2.y);
            const h2 mp0 = __builtin_bit_cast(h2, mv2.x);
            const h2 mp1 = __builtin_bit_cast(h2, mv2.y);
#pragma unroll
            for (int h = 0; h < 2; ++h) {
                accD[h][2 * j]     = fdot2f(mp0, w0[h], accD[h][2 * j]);
                accC[h][2 * j]     = fdot2f(yp0, w1[h], accC[h][2 * j]);
                accD[h][2 * j + 1] = fdot2f(mp1, w0[h], accD[h][2 * j + 1]);
                accC[h][2 * j + 1] = fdot2f(yp1, w1[h], accC[h][2 * j + 1]);
            }
        }
    }

    // ---- 3-step in-register halving ladder over lane bits 5,4,3 ----
    // Units u = h*12+mm (24 real, no pad needed). After the 3 steps, lane ls
    // holds 3 units (base = 6*b4 + 3*b3, h = b5), each summed over the 8-lane
    // orbit {ls ^ span(8,16,32)} (bits 0-2 = ls&7 fixed).
    float2 V[12];
    {
        const bool bit = (ls & 32) != 0;
#pragma unroll
        for (int mm = 0; mm < 12; ++mm) {
            const float2 lo = make_float2(accD[0][mm], accC[0][mm]);
            const float2 hi = make_float2(accD[1][mm], accC[1][mm]);
            const float2 snd = bit ? lo : hi;
            float2 rcv;
#if __has_builtin(__builtin_amdgcn_permlane32_swap)
            {
                auto rx = __builtin_amdgcn_permlane32_swap(
                    __float_as_uint(snd.x), __float_as_uint(snd.x), false, false);
                auto ry2 = __builtin_amdgcn_permlane32_swap(
                    __float_as_uint(snd.y), __float_as_uint(snd.y), false, false);
                rcv.x = __uint_as_float(bit ? rx[0] : rx[1]);   // verified R6
                rcv.y = __uint_as_float(bit ? ry2[0] : ry2[1]);
            }
#else
            rcv.x = __shfl_xor(snd.x, 32, 64);
            rcv.y = __shfl_xor(snd.y, 32, 64);
#endif
            const float2 kp = bit ? hi : lo;
            V[mm] = make_float2(kp.x + rcv.x, kp.y + rcv.y);
        }
    }
    float2 W6[6];
    {
        const bool bit = (ls & 16) != 0;
#pragma unroll
        for (int i = 0; i < 6; ++i) {
            const float2 lo = V[i], hi = V[i + 6];
            const float2 snd = bit ? lo : hi;
            const float2 rcv = swz2<0x401F>(snd);
            const float2 kp  = bit ? hi : lo;
            W6[i] = make_float2(kp.x + rcv.x, kp.y + rcv.y);
        }
    }
    float2 Z[3];
    {
        const bool bit = (ls & 8) != 0;
#pragma unroll
        for (int i = 0; i < 3; ++i) {
            const float2 lo = W6[i], hi = W6[i + 3];
            const float2 snd = bit ? lo : hi;
            const float2 rcv = swz2<0x201F>(snd);
            const float2 kp  = bit ? hi : lo;
            Z[i] = make_float2(kp.x + rcv.x, kp.y + rcv.y);
        }
    }

    // dump 3 float2 per lane
    {
        float* dp = &dmp[(gq * 64 + ls) * 6];
#pragma unroll
        for (int s = 0; s < 3; ++s) *(float2*)&dp[2 * s] = Z[s];
    }
    __syncthreads();

    // ---- phase 2: 192 threads, one (wave, h, mm) unit each: sum 8 partials
    if (tid < 8 * 24) {
        const int wv = tid / 24;
        const int r  = tid % 24;
        const int h  = r / 12;
        const int mm = r % 12;
        const int base_ls = h * 32 + (mm / 6) * 16 + ((mm % 6) / 3) * 8;
        const int s = mm % 3;
        float dens = 0.f, conv = 0.f;
#pragma unroll
        for (int k = 0; k < 8; ++k) {
            const float2 v = *(const float2*)&dmp[((wv * 64 + base_ls + k) * 3 + s) * 2];
            dens += v.x;
            conv += v.y;
        }
        const int g = gb + wv + 8 * h;
        float2 o;
        o.x = dens;
        o.y = conv / (dens + 1e-8f);
        *(float2*)&out[(size_t)(b * G_ + g) * (2 * M_) + 2 * mm] = o;
    }
}

extern "C" void kernel_launch(void* const* d_in, const int* in_sizes, int n_in,
                              void* d_out, int out_size, void* d_ws, size_t ws_size,
                              hipStream_t stream) {
    const float* y     = (const float*)d_in[0];
    const float* x     = (const float*)d_in[1];
    const int*   mask  = (const int*)d_in[2];
    const float* grid  = (const float*)d_in[3];
    const float* sigma = (const float*)d_in[4];
    float* out = (float*)d_out;
    (void)d_ws; (void)ws_size;

    k_fused<<<NBLK, 512, 0, stream>>>(y, x, mask, grid, sigma, out);
}